// Round 4
// baseline (215.809 us; speedup 1.0000x reference)
//
#include <hip/hip_runtime.h>
#include <math.h>

// ConvSlimCapsule3D fused, round 8.
// Shapes fixed: B=2, in_dim=8, in_atoms=16, D=H=W=32, out_dim=8, out_atoms=16, k=3.
// Changes vs round 7 (which was throughput-bound: sum of per-CU pipe work):
//  - wh2 reordered to [c][n][k]: per K-chunk, all 8 waves read the SAME 8KB slab
//    -> L1-resident, per-CU L2 B-traffic 3.6MB -> 0.9MB.
//  - wave tile M32xN128 (id = wid, both voxel halves): A ds_read_b128 56 -> 28
//    per wave (af1 = af0 + 4096B, same swizzle slot).
//  - i-split routing: thread (vv,oo,half) owns in_dims half*4..+3 x all 16 atoms.
//    No ds-shfls (pre-combine via DPP quad_perm VALU swap); sqrt/div halved;
//    a-loops in f32x2 to get v_pk_fma_f32.
//  - FIX latent race: RT (2304 f32) and LG now disjoint (LG = RT + 2304); r7 had
//    RT[vv>=16] aliasing LG[vv<16] with no barrier between RT-read / LG-write.

typedef _Float16 half8 __attribute__((ext_vector_type(8)));
typedef float f32x4 __attribute__((ext_vector_type(4)));
typedef float f32x2 __attribute__((ext_vector_type(2)));

__device__ __forceinline__ void gload_lds16(const void* g, void* l) {
    __builtin_amdgcn_global_load_lds(
        (const __attribute__((address_space(1))) void*)g,
        (__attribute__((address_space(3))) void*)l, 16, 0, 0);
}

// lane^1 exchange on the VALU (DPP quad_perm(1,0,3,2)), not the LDS pipe.
__device__ __forceinline__ float swap1(float x) {
    return __builtin_bit_cast(float, __builtin_amdgcn_update_dpp(
        0, __builtin_bit_cast(int, x), 0xB1, 0xF, 0xF, true));
}
__device__ __forceinline__ f32x2 swap2(f32x2 v) {
    f32x2 r; r[0] = swap1(v[0]); r[1] = swap1(v[1]); return r;
}

// ---- prep 1: cw f32 (n=128, ca=16, tap=27) -> wh2 f16 [c=14][n=128][k=32],
//      k = tp*16+ca, tap = 2c+tp, tap 27 zeroed. ----
__global__ __launch_bounds__(256) void prep_weights(const float* __restrict__ cw,
                                                    _Float16* __restrict__ wh2) {
    const int idx = blockIdx.x * 256 + threadIdx.x;   // 57344
    const int n   = idx / 448;
    const int rem = idx - n * 448;
    const int c   = rem >> 5;
    const int k   = rem & 31;
    const int tp  = k >> 4, ca = k & 15;
    const int tap = 2 * c + tp;
    float v = (tap < 27) ? cw[n * 432 + ca * 27 + tap] : 0.0f;
    wh2[c * 4096 + n * 32 + k] = (_Float16)v;
}

// ---- prep 2: x (2,128,32,32,32) f32 -> xt[b][zp34][yp34][wp34][ch128] f16,
//      1-voxel zero halo. One block per (b,zp,yp) plane; LDS transpose. ----
__global__ __launch_bounds__(256) void prep_xt(const float* __restrict__ x,
                                               _Float16* __restrict__ xt) {
    __shared__ half8 ldsv[544];           // [wp 0..33][ch 0..127] f16 = 8704 B
    _Float16* lds = (_Float16*)ldsv;
    const int t  = threadIdx.x;
    const int bz = blockIdx.x;            // 2*34*34 = 2312
    const int yp = bz % 34;
    const int t2 = bz / 34;
    const int zp = t2 % 34;
    const int b  = t2 / 34;
    _Float16* dst = xt + (size_t)(((b * 34 + zp) * 34 + yp)) * 34 * 128;
    const bool interior = (zp >= 1 && zp <= 32 && yp >= 1 && yp <= 32);
    if (!interior) {
        const half8 z8 = (half8)(_Float16)0.f;
        for (int idx = t; idx < 544; idx += 256)
            *(half8*)(dst + idx * 8) = z8;
        return;
    }
    const int c  = t >> 1;                // 0..127
    const int wh = (t & 1) << 4;          // 0 or 16
    const float* sp = x + (size_t)(b * 128 + c) * 32768
                        + (zp - 1) * 1024 + (yp - 1) * 32 + wh;
    #pragma unroll
    for (int e4 = 0; e4 < 4; e4++) {
        const f32x4 v = *(const f32x4*)(sp + e4 * 4);
        #pragma unroll
        for (int e = 0; e < 4; e++)
            lds[(wh + e4 * 4 + e + 1) * 128 + c] = (_Float16)v[e];
    }
    if (t < 128) lds[t] = (_Float16)0.f;                // wp = 0
    else         lds[33 * 128 + (t - 128)] = (_Float16)0.f; // wp = 33
    __syncthreads();
    for (int idx = t; idx < 544; idx += 256)
        *(half8*)(dst + idx * 8) = *(const half8*)(lds + idx * 8);
}

__global__ __launch_bounds__(512, 4) void caps_mfma_kernel(
    const _Float16* __restrict__ xt,  // (2,34,34,34,128) f16 padded
    const _Float16* __restrict__ wh2, // (14,128,32) f16 reordered
    const float* __restrict__ cb,     // (128,)
    const float* __restrict__ bias,   // (8,16)
    float* __restrict__ out)          // (2,8,16,32,32,32) f32
{
    // 78,848 B: slab = 306 live rows (zy 0..8 x j 0..33) + 2 phantom, x 256B.
    // Votes (66,048B) overlay slab after B1; RT(2304 f32)+LG(2304 f32) after B3.
    __shared__ half8 slabv[4928];
    char* smem = (char*)slabv;
    _Float16* Vh = (_Float16*)slabv;
    float* RT = (float*)slabv;
    float* LG = (float*)slabv + 2304;

    const int t  = threadIdx.x;
    const int bx = blockIdx.x;
    const int gid = ((bx & 7) << 8) | (bx >> 3);   // XCD-contiguous (2048 = 8*256)
    const int h = gid & 31;
    const int d = (gid >> 5) & 31;
    const int b = gid >> 10;

    const int wid = t >> 6, lane = t & 63;

    // ================= stage slab: 308 rows x 256B via global_load_lds ============
    // row rr = zy*34 + j holds, at slot s, ch-unit u = s ^ (j&15). One instruction
    // = 4 rows; phantom rows 306/307 read a valid source (data unused).
    {
        const int lrow = lane >> 4;        // 0..3
        const int s    = lane & 15;
        const int bzd  = b * 34 + d;
        for (int i = wid; i < 77; i += 8) {
            const int rr0 = i << 2;        // 0..304
            const int rr  = rr0 + lrow;    // 0..307
            int zy = rr / 34;              // 0..9
            int j  = rr - zy * 34;
            if (rr >= 306) { zy = 0; j = 0; }   // phantom
            const int dz  = (zy * 11) >> 5; // zy/3 for zy<=8
            const int dy  = zy - dz * 3;
            const int uu  = s ^ (j & 15);
            const unsigned off =
                ((((unsigned)(bzd + dz) * 34u + (unsigned)(h + dy)) * 34u
                  + (unsigned)j) << 8) + (unsigned)(uu << 4);
            gload_lds16((const char*)xt + off, smem + (rr0 << 8));
        }
    }
    __syncthreads();   // B0: vmcnt drained by barrier -> slab staged

    // ================= GEMM: M=256, N=128, K=448; wave tile M32xN128 ==============
    const int q = lane >> 4, r = lane & 15;
    const int qlow = q & 1, tphase = q >> 1;

    int zyA[14], dxA[14];
    #pragma unroll
    for (int c = 0; c < 14; c++) {
        int tap = 2 * c + tphase;          // 0..27
        if (tap > 26) tap = 0;             // tap27: B weights are zero
        const int dz = tap / 9, r9 = tap - dz * 9;
        const int dy = r9 / 3,  dxx = r9 - dy * 3;
        zyA[c] = dz * 3 + dy;
        dxA[c] = dxx;
    }
    const int uA = wid * 2 + qlow;         // ch-unit for in_dim = wid

    const _Float16* bp0 = wh2 + r * 32 + q * 8;          // + c*4096 + nt*512
    const _Float16* bp1 = bp0 + 2048;

    f32x4 acc[2][8];
    #pragma unroll
    for (int i = 0; i < 2; i++)
        #pragma unroll
        for (int j = 0; j < 8; j++) acc[i][j] = (f32x4)0.f;

    #pragma unroll
    for (int c = 0; c < 14; c++) {
        half8 bf[8];
        #pragma unroll
        for (int nt = 0; nt < 4; nt++) {
            bf[nt]     = *(const half8*)(bp0 + c * 4096 + nt * 512);
            bf[nt + 4] = *(const half8*)(bp1 + c * 4096 + nt * 512);
        }
        const int jw = r + dxA[c];
        const int js = jw & 15;
        const char* abase = smem + zyA[c] * 8704 + jw * 256 + ((uA ^ js) << 4);
        const half8 af0 = *(const half8*)abase;            // voxel half 0
        const half8 af1 = *(const half8*)(abase + 4096);   // voxel half 1 (+16 rows)
        #pragma unroll
        for (int nt = 0; nt < 8; nt++) {
            acc[0][nt] = __builtin_amdgcn_mfma_f32_16x16x32_f16(af0, bf[nt],
                                                                acc[0][nt], 0, 0, 0);
            acc[1][nt] = __builtin_amdgcn_mfma_f32_16x16x32_f16(af1, bf[nt],
                                                                acc[1][nt], 0, 0, 0);
        }
    }

    __syncthreads();   // B1: all slab reads done -> votes may overlay the slab

    // ================= epilogue: votes (+conv bias) f16, overlaying the slab =======
    float cbv[8];
    #pragma unroll
    for (int nt = 0; nt < 8; nt++) cbv[nt] = cb[nt * 16 + r];
    #pragma unroll
    for (int mt = 0; mt < 2; mt++) {
        #pragma unroll
        for (int nt = 0; nt < 8; nt++) {
            const int n = nt * 16 + r;
            #pragma unroll
            for (int reg = 0; reg < 4; reg++) {
                const int v = mt * 16 + q * 4 + reg;     // voxel 0..31
                Vh[v * 1032 + wid * 128 + n] = (_Float16)(acc[mt][nt][reg] + cbv[nt]);
            }
        }
    }
    __syncthreads();   // B2: all vote writes visible

    // ============ routing: 512 threads = 256 (v,o) pairs x 2 in_dim-halves =========
    const int p = t >> 1, half = t & 1;
    const int vv = p & 31, oo = p >> 5;   // also coop-softmax task (v2=vv, i2=oo)
    const int ib = half << 2;             // own in_dims ib..ib+3

    f32x2 vf2[4][8];                      // [own i][atom pair] (all 16 atoms)
    #pragma unroll
    for (int ii = 0; ii < 4; ii++) {
        #pragma unroll
        for (int ah = 0; ah < 2; ah++) {
            const half8 hv =
                *(const half8*)&Vh[vv * 1032 + (ib + ii) * 128 + oo * 16 + ah * 8];
            #pragma unroll
            for (int k = 0; k < 4; k++) {
                f32x2 e; e[0] = (float)hv[2 * k]; e[1] = (float)hv[2 * k + 1];
                vf2[ii][ah * 4 + k] = e;
            }
        }
    }
    __syncthreads();   // B3: vote reads done -> RT/LG may overlay vote region

    float vn[4];
    #pragma unroll
    for (int ii = 0; ii < 4; ii++) {
        f32x2 s = (f32x2)0.f;
        #pragma unroll
        for (int k = 0; k < 8; k++)
            s = __builtin_elementwise_fma(vf2[ii][k], vf2[ii][k], s);
        vn[ii] = sqrtf(s[0] + s[1]);
    }
    f32x2 bl2[8];
    #pragma unroll
    for (int k = 0; k < 8; k++)
        bl2[k] = *(const f32x2*)&bias[oo * 16 + 2 * k];

    float rt[4], lgr[4];
    #pragma unroll
    for (int ii = 0; ii < 4; ii++) { rt[ii] = 0.125f; lgr[ii] = 0.f; }
    f32x2 pre2[8];

    for (int it = 0; it < 3; it++) {
        #pragma unroll
        for (int k = 0; k < 8; k++) pre2[k] = (f32x2)0.f;
        #pragma unroll
        for (int ii = 0; ii < 4; ii++) {
            f32x2 rtv; rtv[0] = rt[ii]; rtv[1] = rt[ii];
            #pragma unroll
            for (int k = 0; k < 8; k++)
                pre2[k] = __builtin_elementwise_fma(rtv, vf2[ii][k], pre2[k]);
        }
        #pragma unroll
        for (int k = 0; k < 8; k++)
            pre2[k] = bl2[k] + pre2[k] + swap2(pre2[k]);   // combine i-halves
        if (it == 2) break;

        f32x2 s2v = (f32x2)0.f;
        #pragma unroll
        for (int k = 0; k < 8; k++)
            s2v = __builtin_elementwise_fma(pre2[k], pre2[k], s2v);
        const float pn = sqrtf(s2v[0] + s2v[1]);

        #pragma unroll
        for (int ii = 0; ii < 4; ii++) {
            f32x2 dv = (f32x2)0.f;
            #pragma unroll
            for (int k = 0; k < 8; k++)
                dv = __builtin_elementwise_fma(pre2[k], vf2[ii][k], dv);
            lgr[ii] += __fdividef(dv[0] + dv[1], fmaxf(pn * vn[ii], 1e-8f));
            LG[vv * 72 + (ib + ii) * 8 + oo] = lgr[ii];
        }
        __syncthreads();   // LG writes visible

        // coop softmax over o for task (v2=vv, i2=oo); |logit| <= 2 -> no max-sub
        {
            const f32x4 E = *(const f32x4*)&LG[vv * 72 + oo * 8 + half * 4];
            f32x4 ex; float ps = 0.f;
            #pragma unroll
            for (int k = 0; k < 4; k++) { ex[k] = __expf(E[k]); ps += ex[k]; }
            const float sum = ps + swap1(ps);
            const float rs = __fdividef(1.f, sum);
            f32x4 w4;
            #pragma unroll
            for (int k = 0; k < 4; k++) w4[k] = ex[k] * rs;
            *(f32x4*)&RT[vv * 72 + oo * 8 + half * 4] = w4;
        }
        __syncthreads();   // RT writes visible

        #pragma unroll
        for (int ii = 0; ii < 4; ii++)
            rt[ii] = RT[vv * 72 + (ib + ii) * 8 + oo];
    }

    // ---- squash + store (full pre held by both halves; each stores 8 atoms) ----
    f32x2 s2v = (f32x2)0.f;
    #pragma unroll
    for (int k = 0; k < 8; k++)
        s2v = __builtin_elementwise_fma(pre2[k], pre2[k], s2v);
    const float n2 = s2v[0] + s2v[1];
    const float nn = sqrtf(n2);
    const float scale = __fdividef(n2, (1.f + n2) * (nn + 1e-12f));
    const size_t sp = (size_t)d * 1024 + h * 32 + vv;
    #pragma unroll
    for (int a = 0; a < 8; a++) {
        const float vlo = pre2[(a >> 1)][a & 1];       // atoms 0..7
        const float vhi = pre2[4 + (a >> 1)][a & 1];   // atoms 8..15
        const float pv  = half ? vhi : vlo;
        out[((size_t)((b * 8 + oo) * 16 + half * 8 + a)) * 32768 + sp] = pv * scale;
    }
}

extern "C" void kernel_launch(void* const* d_in, const int* in_sizes, int n_in,
                              void* d_out, int out_size, void* d_ws, size_t ws_size,
                              hipStream_t stream) {
    const float* x    = (const float*)d_in[0];
    const float* cw   = (const float*)d_in[1];
    const float* cb   = (const float*)d_in[2];
    const float* bias = (const float*)d_in[3];
    float* out = (float*)d_out;
    _Float16* wh2 = (_Float16*)d_ws;                     // 114,688 B
    _Float16* xt  = (_Float16*)((char*)d_ws + 114688);   // 20,123,648 B

    hipLaunchKernelGGL(prep_weights, dim3(224), dim3(256), 0, stream, cw, wh2);
    hipLaunchKernelGGL(prep_xt, dim3(2312), dim3(256), 0, stream, x, xt);
    hipLaunchKernelGGL(caps_mfma_kernel, dim3(2048), dim3(512), 0, stream,
                       xt, wh2, cb, bias, out);
}